// Round 1
// baseline (259.774 us; speedup 1.0000x reference)
//
#include <hip/hip_runtime.h>
#include <hip/hip_bf16.h>
#include <math.h>

#define NB 256
#define SS 512
#define LL 128

typedef short bf16x8 __attribute__((ext_vector_type(8)));
typedef float f32x4 __attribute__((ext_vector_type(4)));

typedef __attribute__((address_space(1))) const unsigned int GU32;
typedef __attribute__((address_space(3))) unsigned int LU32;

__device__ __forceinline__ short f2bf(float f) {
    __hip_bfloat16 h = __float2bfloat16(f);
    short s;
    __builtin_memcpy(&s, &h, 2);
    return s;
}

// Stage 32 feature rows (16 KB f32) global->LDS via direct-to-LDS DMA.
// dst must be wave-uniform; HW writes lane i's 16 B at dst + 16*i, and the
// per-lane global src carries the matching +16*i (src includes tid*4 floats).
__device__ __forceinline__ void stage32rows(const float* src, float* dst) {
#pragma unroll
    for (int i = 0; i < 16; ++i)
        __builtin_amdgcn_global_load_lds((GU32*)(src + i * 256),
                                         (LU32*)(dst + i * 256), 16, 0, 0);
}

// One block = ONE WAVE (64 threads) = one full chain (fwd or bwd) of one batch.
// grid = 512: blocks 0..255 fwd, 256..511 bwd -> ~2 independent waves/CU.
// No __syncthreads anywhere: publish is 2 ds_write_b16/lane, consumed by the
// same wave (in-order LDS + lgkmcnt guard). Transition matrix exp(T) lives
// entirely in VGPRs (8 N-tiles x 4 K-tiles of bf16x8 = 128 VGPRs).
// Per round: publish u -> lgkmcnt(0) -> 4 broadcast ds_read_b128 -> 32 MFMAs
// (C rows all equal u => reg0 is the matvec) -> select/exp. Features are f32,
// staged in 32-row double-buffered LDS chunks via global_load_lds, prefetched
// 32 rounds ahead (one vmcnt(0) per 32 rounds, at the last round of a chunk).
// exp(f_t) for round r+1 is computed during round r (off the critical path).
__global__ __launch_bounds__(64, 1) void crf_chain_kernel(
    const float* __restrict__ feats,    // (B,S,L)
    const float* __restrict__ start_t,  // (L)
    const float* __restrict__ end_t,    // (L)
    const float* __restrict__ trans,    // (L,L)
    const int* __restrict__ mask,       // (B,S)
    const int* __restrict__ labels,     // (B,S)
    float* __restrict__ ws)
{
    const int bid = blockIdx.x;
    const int b = bid & 255;
    const int isB = bid >> 8;   // 0 = forward chain, 1 = backward chain
    const int tid = threadIdx.x;
    const int l15 = tid & 15;
    const int g = tid >> 4;

    __shared__ __align__(16) short img[2][LL];      // u image, bf16, dbuf (512 B)
    __shared__ __align__(16) float fS[2][32][LL];   // feature chunks, f32 (32 KB)
    __shared__ int lmask[SS];                       // 2 KB

    const float* fb = feats + (size_t)b * SS * LL;

    // ---- stage chunk 0 (fwd rows 1..32 / bwd rows 480..511); latency hides
    //      under the E-fragment build below ----
    {
        const int rb = isB ? 480 : 1;
        stage32rows(fb + rb * LL + tid * 4, &fS[0][0][0]);
    }

    // ---- stage masks (same-wave LDS, no barrier needed) ----
#pragma unroll
    for (int q = 0; q < 8; ++q) lmask[tid + 64 * q] = mask[b * SS + tid + 64 * q];

    // ---- exp(transition) B-fragments, whole matrix resident in VGPRs ----
    // fwd: B[k][n] = exp(T[k][n]); bwd: B[k=j][n=i] = exp(T[i][j]) (= T^T)
    bf16x8 Bf[8][4];
#pragma unroll
    for (int nt = 0; nt < 8; ++nt) {
        const int n = 16 * nt + l15;
#pragma unroll
        for (int kt = 0; kt < 4; ++kt) {
            bf16x8 fr;
#pragma unroll
            for (int j = 0; j < 8; ++j) {
                const int k = 32 * kt + 8 * g + j;
                float tv = isB ? trans[n * LL + k] : trans[k * LL + n];
                fr[j] = f2bf(__expf(tv));
            }
            Bf[nt][kt] = fr;
        }
    }

    // ---- chain state: v[nt] = value at position 16*nt + l15 (replicated x4 g) ----
    float v[8];
#pragma unroll
    for (int nt = 0; nt < 8; ++nt) {
        const int p = 16 * nt + l15;
        v[nt] = isB ? __expf(end_t[p]) : __expf(start_t[p] + fb[p]);
    }

    asm volatile("s_waitcnt vmcnt(0)" ::: "memory");  // chunk 0 landed

    // ---- prefetch chunk 1 (fwd rows 33..64 / bwd rows 448..479) ----
    {
        const int rb = isB ? 448 : 33;
        stage32rows(fb + rb * LL + tid * 4, &fS[1][0][0]);
    }

    // ---- exp(features) for round 0 (fwd row 1 = slot 0; bwd row 511 = slot 31) ----
    float eft[8];
    {
        const float* fr0 = &fS[0][isB ? 31 : 0][0];
#pragma unroll
        for (int nt = 0; nt < 8; ++nt) eft[nt] = __expf(fr0[16 * nt + l15]);
    }

    int eacc = 0;

    for (int r = 0; r < 256; ++r) {
        // chunk c+1 was issued 31 rounds ago; wait here so that this round's
        // next-feature read (which crosses into it) is safe.
        if ((r & 31) == 31 && r != 255)
            asm volatile("s_waitcnt vmcnt(0)" ::: "memory");
        // first round of chunk c: prefetch chunk c+1 into the other buffer
        // (its previous contents were last read 2 rounds ago).
        if ((r & 31) == 0 && r != 0 && r <= 192) {
            const int cN = (r >> 5) + 1;
            const int rb = isB ? (480 - 32 * cN) : (32 * cN + 1);
            stage32rows(fb + rb * LL + tid * 4, &fS[cN & 1][0][0]);
        }

        const int t = isB ? (511 - r) : (r + 1);
        int mt = lmask[t];
        if (!isB && r == 255) mt = 0;  // fwd dummy round

        // ---- publish: each lane writes tiles 2g, 2g+1 (each position once) ----
        // fwd publishes alpha_{t-1}; bwd publishes exp(f_t)*beta_t
        float we = (g < 2) ? (g == 0 ? v[0] : v[2]) : (g == 2 ? v[4] : v[6]);
        float wo = (g < 2) ? (g == 0 ? v[1] : v[3]) : (g == 2 ? v[5] : v[7]);
        if (isB) {
            float ee = (g < 2) ? (g == 0 ? eft[0] : eft[2]) : (g == 2 ? eft[4] : eft[6]);
            float eo = (g < 2) ? (g == 0 ? eft[1] : eft[3]) : (g == 2 ? eft[5] : eft[7]);
            we *= ee;
            wo *= eo;
        }
        short* ib = &img[r & 1][0];
        ib[32 * g + l15] = f2bf(we);
        ib[32 * g + 16 + l15] = f2bf(wo);

        // same-wave RAW through LDS: drain writes before the fragment reads
        asm volatile("s_waitcnt lgkmcnt(0)" ::: "memory");

        const bf16x8* ip = (const bf16x8*)ib;
        bf16x8 a0 = ip[g], a1 = ip[4 + g], a2 = ip[8 + g], a3 = ip[12 + g];

        // next round's raw features (off the critical path; exp'd after MFMA)
        float fnx[8];
        const int rn = r + 1;
        if (rn < 256) {
            const float* frn = &fS[(rn >> 5) & 1][isB ? (31 - (rn & 31)) : (rn & 31)][0];
#pragma unroll
            for (int nt = 0; nt < 8; ++nt) fnx[nt] = frn[16 * nt + l15];
        }

        f32x4 cc[8];
#pragma unroll
        for (int nt = 0; nt < 8; ++nt) cc[nt] = (f32x4){0.f, 0.f, 0.f, 0.f};
#pragma unroll
        for (int nt = 0; nt < 8; ++nt)
            cc[nt] = __builtin_amdgcn_mfma_f32_16x16x32_bf16(a0, Bf[nt][0], cc[nt], 0, 0, 0);
#pragma unroll
        for (int nt = 0; nt < 8; ++nt)
            cc[nt] = __builtin_amdgcn_mfma_f32_16x16x32_bf16(a1, Bf[nt][1], cc[nt], 0, 0, 0);
#pragma unroll
        for (int nt = 0; nt < 8; ++nt)
            cc[nt] = __builtin_amdgcn_mfma_f32_16x16x32_bf16(a2, Bf[nt][2], cc[nt], 0, 0, 0);
#pragma unroll
        for (int nt = 0; nt < 8; ++nt)
            cc[nt] = __builtin_amdgcn_mfma_f32_16x16x32_bf16(a3, Bf[nt][3], cc[nt], 0, 0, 0);

        // ---- epilogue: all C rows equal -> reg0 is the matvec result ----
#pragma unroll
        for (int nt = 0; nt < 8; ++nt) {
            float cpre = cc[nt][0];
            float cand = isB ? cpre : eft[nt] * cpre;
            v[nt] = mt ? cand : v[nt];
        }

        // exp(features) for the next round (overlaps with nothing critical)
        if (rn < 256) {
#pragma unroll
            for (int nt = 0; nt < 8; ++nt) eft[nt] = __expf(fnx[nt]);
        }

        // ---- rescale every 8 rounds (exact power-of-2, exponent recorded) ----
        if ((r & 7) == 7) {
            float s = ((v[0] + v[1]) + (v[2] + v[3])) + ((v[4] + v[5]) + (v[6] + v[7]));
            s += __shfl_xor(s, 1);
            s += __shfl_xor(s, 2);
            s += __shfl_xor(s, 4);
            s += __shfl_xor(s, 8);
            int ex;
            frexpf(s, &ex);
#pragma unroll
            for (int nt = 0; nt < 8; ++nt) v[nt] = ldexpf(v[nt], -ex);
            eacc += ex;
        }
    }

    // ---- workspace layout ----
    float* av = ws;                      // alpha_255 (B,L)
    float* bv = ws + NB * LL;            // beta_255  (B,L)
    float* eFa = ws + 2 * NB * LL;       // fwd exponents (B)
    float* eBa = eFa + NB;               // bwd exponents (B)
    float* nFa = eBa + NB;               // numerator partial, tt in [0,256)
    float* nBa = nFa + NB;               // numerator partial, tt in [256,512)
    float* cFa = nBa + NB;               // mask-count partial
    float* cBa = cFa + NB;

    if (g == 0) {
#pragma unroll
        for (int nt = 0; nt < 8; ++nt)
            (isB ? bv : av)[b * LL + 16 * nt + l15] = v[nt];
    }
    if (tid == 0) (isB ? eBa : eFa)[b] = (float)eacc;

    // ---- numerator half (gold path, fp32 exact): fwd does tt 0..255, bwd 256..511 ----
    {
        const int* lb = labels + b * SS;
        const int* mb = mask + b * SS;
        float term = 0.f;
        int cnt = 0;
#pragma unroll
        for (int q = 0; q < 4; ++q) {
            const int tt = isB * 256 + tid + 64 * q;
            int l = lb[tt];
            if ((unsigned)l >= LL) l = 0;
            const int m = mb[tt];
            cnt += (m != 0);
            if (tt == 0) {
                term += start_t[l] + fb[l];
            } else if (m) {
                int lp = lb[tt - 1];
                if ((unsigned)lp >= LL) lp = 0;
                term += trans[lp * LL + l] + fb[(size_t)tt * LL + l];
            }
        }
#pragma unroll
        for (int o = 1; o < 64; o <<= 1) {
            term += __shfl_xor(term, o);
            cnt += __shfl_xor(cnt, o);
        }
        if (tid == 0) {
            (isB ? nBa : nFa)[b] = term;
            (isB ? cBa : cFa)[b] = (float)cnt;
        }
    }
}

// Combine: Z = sum_i alpha_255[i]*beta_255[i] * 2^(eF+eB); add the end-tag
// numerator term (needs the full mask count); weighted-mean reduce.
__global__ __launch_bounds__(256) void crf_final_kernel(
    const float* __restrict__ ws, const float* __restrict__ conf,
    const float* __restrict__ end_t, const int* __restrict__ labels,
    float* __restrict__ out)
{
    const int tid = threadIdx.x;  // = batch index
    const float* av = ws;
    const float* bv = ws + NB * LL;
    const float* eFa = ws + 2 * NB * LL;
    const float* eBa = eFa + NB;
    const float* nFa = eBa + NB;
    const float* nBa = nFa + NB;
    const float* cFa = nBa + NB;
    const float* cBa = cFa + NB;

    const float4* a4 = (const float4*)(av + tid * LL);
    const float4* b4 = (const float4*)(bv + tid * LL);
    float dot = 0.f;
#pragma unroll 8
    for (int k = 0; k < 32; ++k) {
        float4 a = a4[k], bb = b4[k];
        dot += a.x * bb.x + a.y * bb.y + a.z * bb.z + a.w * bb.w;
    }
    int c = (int)(cFa[tid] + cBa[tid]);
    int sl = c - 1;
    sl = sl < 0 ? 0 : (sl >= SS ? SS - 1 : sl);
    int lt = labels[tid * SS + sl];
    if ((unsigned)lt >= LL) lt = 0;
    float lognum = nFa[tid] + nBa[tid] + end_t[lt];
    float logZ = logf(dot) + 0.69314718055994531f * (eFa[tid] + eBa[tid]);
    float loss = (logZ - lognum) * conf[tid] * (1.0f / NB);

#pragma unroll
    for (int o = 1; o < 64; o <<= 1) loss += __shfl_xor(loss, o);
    __shared__ float red[4];
    if ((tid & 63) == 0) red[tid >> 6] = loss;
    __syncthreads();
    if (tid == 0) out[0] = red[0] + red[1] + red[2] + red[3];
}

extern "C" void kernel_launch(void* const* d_in, const int* in_sizes, int n_in,
                              void* d_out, int out_size, void* d_ws, size_t ws_size,
                              hipStream_t stream) {
    const float* feats  = (const float*)d_in[0];
    const float* startt = (const float*)d_in[1];
    const float* endt   = (const float*)d_in[2];
    const float* trans  = (const float*)d_in[3];
    const float* conf   = (const float*)d_in[4];
    const int*   mask   = (const int*)d_in[5];
    const int*   labels = (const int*)d_in[6];
    float* out = (float*)d_out;
    float* ws = (float*)d_ws;  // needs (2*256*128 + 6*256) floats = ~262 KB

    hipLaunchKernelGGL(crf_chain_kernel, dim3(2 * NB), dim3(64), 0, stream,
                       feats, startt, endt, trans, mask, labels, ws);
    hipLaunchKernelGGL(crf_final_kernel, dim3(1), dim3(256), 0, stream,
                       ws, conf, endt, labels, out);
}